// Round 1
// baseline (8377.058 us; speedup 1.0000x reference)
//
#include <hip/hip_runtime.h>
#include <hip/hip_bf16.h>

#define BATCH 4096

// ---------------------------------------------------------------------------
// Kernel A: fully fused CNN per image. One block (256 threads) per image.
// All intermediates live in LDS (bf16, zero-padded borders). fp32 accumulate.
// Writes the 128-d CNN feature for each image to bf_out (= d_out h region).
// ---------------------------------------------------------------------------
__global__ __launch_bounds__(256, 2) void cnn_fused_kernel(
    const float* __restrict__ board,
    const float* __restrict__ w1, const float* __restrict__ b1,
    const float* __restrict__ w2, const float* __restrict__ b2,
    const float* __restrict__ w3, const float* __restrict__ b3,
    const float* __restrict__ w4, const float* __restrict__ b4,
    const float* __restrict__ pw, const float* __restrict__ pb,
    float* __restrict__ bf_out)
{
    __shared__ alignas(16) float sb[34][34];                 // padded board
    __shared__ alignas(16) __hip_bfloat16 a1[16][34][34];    // conv1 out, padded
    __shared__ alignas(16) __hip_bfloat16 p2[32][18][18];    // pooled conv2, padded
    __shared__ alignas(16) __hip_bfloat16 p3[64][10][10];    // pooled conv3, padded
    __shared__ float sums[128][2];
    __shared__ float meanv[128];

    const int t = threadIdx.x;
    const int img = blockIdx.x;

    // ---- zero all padded LDS arrays (borders must be 0) ----
    {
        uint32_t* z;
        z = (uint32_t*)&sb[0][0];
        for (int i = t; i < 34 * 34; i += 256) z[i] = 0u;
        z = (uint32_t*)&a1[0][0][0];
        for (int i = t; i < 16 * 34 * 34 / 2; i += 256) z[i] = 0u;
        z = (uint32_t*)&p2[0][0][0];
        for (int i = t; i < 32 * 18 * 18 / 2; i += 256) z[i] = 0u;
        z = (uint32_t*)&p3[0][0][0];
        for (int i = t; i < 64 * 10 * 10 / 2; i += 256) z[i] = 0u;
    }
    __syncthreads();

    // ---- load board into padded LDS ----
    for (int p = t; p < 1024; p += 256) {
        sb[(p >> 5) + 1][(p & 31) + 1] = board[img * 1024 + p];
    }
    __syncthreads();

    // ---- conv1: 1->16 ch, 32x32, relu ----
    {
        const int oc = t >> 4;        // 0..15
        const int l16 = t & 15;
        float w[9];
#pragma unroll
        for (int k = 0; k < 9; ++k) w[k] = w1[oc * 9 + k];
        const float bias = b1[oc];
        for (int j = 0; j < 64; ++j) {
            const int p = l16 + (j << 4);        // 0..1023
            const int y = p >> 5, x = p & 31;
            float acc = bias;
#pragma unroll
            for (int dy = 0; dy < 3; ++dy)
#pragma unroll
                for (int dx = 0; dx < 3; ++dx)
                    acc = fmaf(sb[y + dy][x + dx], w[dy * 3 + dx], acc);
            a1[oc][y + 1][x + 1] = __float2bfloat16(fmaxf(acc, 0.f));
        }
    }
    __syncthreads();

    // ---- conv2 (16->32) + relu + maxpool2 -> p2 [32][16][16] ----
    {
        const int oc = t >> 3;       // 0..31
        const int sub = t & 7;
        const float bias = b2[oc];
        const float* wbase = w2 + oc * 16 * 9;
#pragma unroll 1
        for (int ch = 0; ch < 4; ++ch) {          // 4 chunks of 8 pooled cells
            float acc[8][4];
#pragma unroll
            for (int jj = 0; jj < 8; ++jj)
#pragma unroll
                for (int s = 0; s < 4; ++s) acc[jj][s] = bias;
            const int cp0 = sub + (ch << 6);
            for (int ic = 0; ic < 16; ++ic) {
                float w[9];
#pragma unroll
                for (int k = 0; k < 9; ++k) w[k] = wbase[ic * 9 + k];
#pragma unroll
                for (int jj = 0; jj < 8; ++jj) {
                    const int cp = cp0 + (jj << 3);      // 0..255
                    const int py = cp >> 4, px = cp & 15;
                    float v[4][4];
#pragma unroll
                    for (int r = 0; r < 4; ++r)
#pragma unroll
                        for (int c = 0; c < 4; ++c)
                            v[r][c] = __bfloat162float(a1[ic][2 * py + r][2 * px + c]);
#pragma unroll
                    for (int sy = 0; sy < 2; ++sy)
#pragma unroll
                        for (int sx = 0; sx < 2; ++sx)
#pragma unroll
                            for (int dy = 0; dy < 3; ++dy)
#pragma unroll
                                for (int dx = 0; dx < 3; ++dx)
                                    acc[jj][sy * 2 + sx] = fmaf(v[sy + dy][sx + dx], w[dy * 3 + dx],
                                                                acc[jj][sy * 2 + sx]);
                }
            }
#pragma unroll
            for (int jj = 0; jj < 8; ++jj) {
                const int cp = cp0 + (jj << 3);
                const int py = cp >> 4, px = cp & 15;
                float m = fmaxf(fmaxf(acc[jj][0], acc[jj][1]), fmaxf(acc[jj][2], acc[jj][3]));
                p2[oc][py + 1][px + 1] = __float2bfloat16(fmaxf(m, 0.f));
            }
        }
    }
    __syncthreads();

    // ---- conv3 (32->64) + relu + maxpool2 -> p3 [64][8][8] ----
    {
        const int oc = t >> 2;       // 0..63
        const int sub = t & 3;
        const float bias = b3[oc];
        const float* wbase = w3 + oc * 32 * 9;
#pragma unroll 1
        for (int ch = 0; ch < 2; ++ch) {          // 2 chunks of 8 pooled cells
            float acc[8][4];
#pragma unroll
            for (int jj = 0; jj < 8; ++jj)
#pragma unroll
                for (int s = 0; s < 4; ++s) acc[jj][s] = bias;
            const int cp0 = sub + (ch << 5);
            for (int ic = 0; ic < 32; ++ic) {
                float w[9];
#pragma unroll
                for (int k = 0; k < 9; ++k) w[k] = wbase[ic * 9 + k];
#pragma unroll
                for (int jj = 0; jj < 8; ++jj) {
                    const int cp = cp0 + (jj << 2);      // 0..63
                    const int py = cp >> 3, px = cp & 7;
                    float v[4][4];
#pragma unroll
                    for (int r = 0; r < 4; ++r)
#pragma unroll
                        for (int c = 0; c < 4; ++c)
                            v[r][c] = __bfloat162float(p2[ic][2 * py + r][2 * px + c]);
#pragma unroll
                    for (int sy = 0; sy < 2; ++sy)
#pragma unroll
                        for (int sx = 0; sx < 2; ++sx)
#pragma unroll
                            for (int dy = 0; dy < 3; ++dy)
#pragma unroll
                                for (int dx = 0; dx < 3; ++dx)
                                    acc[jj][sy * 2 + sx] = fmaf(v[sy + dy][sx + dx], w[dy * 3 + dx],
                                                                acc[jj][sy * 2 + sx]);
                }
            }
#pragma unroll
            for (int jj = 0; jj < 8; ++jj) {
                const int cp = cp0 + (jj << 2);
                const int py = cp >> 3, px = cp & 7;
                float m = fmaxf(fmaxf(acc[jj][0], acc[jj][1]), fmaxf(acc[jj][2], acc[jj][3]));
                p3[oc][py + 1][px + 1] = __float2bfloat16(fmaxf(m, 0.f));
            }
        }
    }
    __syncthreads();

    // ---- conv4 (64->128) + relu + global avg ----
    {
        const int oc = t >> 1;       // 0..127
        const int sub = t & 1;       // row half
        const float* wbase = w4 + oc * 64 * 9;
        float acc[8][4];
#pragma unroll
        for (int blk = 0; blk < 8; ++blk)
#pragma unroll
            for (int s = 0; s < 4; ++s) acc[blk][s] = 0.f;
        for (int ic = 0; ic < 64; ++ic) {
            float w[9];
#pragma unroll
            for (int k = 0; k < 9; ++k) w[k] = wbase[ic * 9 + k];
#pragma unroll
            for (int blk = 0; blk < 8; ++blk) {
                const int by = blk >> 2, bx = blk & 3;
                const int r0 = 4 * sub + 2 * by, c0 = 2 * bx;   // padded coords
                float v[4][4];
#pragma unroll
                for (int r = 0; r < 4; ++r)
#pragma unroll
                    for (int c = 0; c < 4; ++c)
                        v[r][c] = __bfloat162float(p3[ic][r0 + r][c0 + c]);
#pragma unroll
                for (int sy = 0; sy < 2; ++sy)
#pragma unroll
                    for (int sx = 0; sx < 2; ++sx)
#pragma unroll
                        for (int dy = 0; dy < 3; ++dy)
#pragma unroll
                            for (int dx = 0; dx < 3; ++dx)
                                acc[blk][sy * 2 + sx] = fmaf(v[sy + dy][sx + dx], w[dy * 3 + dx],
                                                             acc[blk][sy * 2 + sx]);
            }
        }
        const float bias = b4[oc];
        float partial = 0.f;
#pragma unroll
        for (int blk = 0; blk < 8; ++blk)
#pragma unroll
            for (int s = 0; s < 4; ++s) partial += fmaxf(acc[blk][s] + bias, 0.f);
        sums[oc][sub] = partial;
    }
    __syncthreads();
    if (t < 128) meanv[t] = (sums[t][0] + sums[t][1]) * (1.f / 64.f);
    __syncthreads();

    // ---- proj: [128] @ proj_w.T + proj_b ----
    if (t < 128) {
        float acc = pb[t];
        const float* w = pw + t * 128;
        for (int k = 0; k < 128; ++k) acc = fmaf(meanv[k], w[k], acc);
        bf_out[img * 128 + t] = acc;
    }
}

// ---------------------------------------------------------------------------
// Kernel B: GRU step + head. 8 rows per block, 384 threads (one per gate out).
// CNN features are read from out+24576 (h region) and then overwritten with
// h_new by the same block (reads complete before writes; rows are exclusive).
// ---------------------------------------------------------------------------
__global__ __launch_bounds__(384) void gru_kernel(
    const float* __restrict__ hin,
    const int* __restrict__ atok, const int* __restrict__ uidx,
    const float* __restrict__ emb,
    const float* __restrict__ w_ih, const float* __restrict__ w_hh,
    const float* __restrict__ b_ih, const float* __restrict__ b_hh,
    const float* __restrict__ head_w, const float* __restrict__ head_b,
    float* __restrict__ out)
{
    const int img0 = blockIdx.x * 8;
    const int t = threadIdx.x;
    __shared__ float xin_s[8][168];
    __shared__ float h0_s[8][128];
    __shared__ float gis[8][384];
    __shared__ float ghs[8][384];
    __shared__ float hn_s[8][128];
    const float* bf = out + BATCH * 6;   // CNN features stashed in h region

    // stage xin = [cnn_feat(128) | action_bits(8) | user_emb(32)]
    for (int idx = t; idx < 8 * 168; idx += 384) {
        const int r = idx / 168, k = idx - r * 168;
        const int row = img0 + r;
        float v;
        if (k < 128)      v = bf[row * 128 + k];
        else if (k < 136) v = (float)((atok[row] >> (k - 128)) & 1);
        else              v = emb[uidx[row] * 32 + (k - 136)];
        xin_s[r][k] = v;
    }
    for (int idx = t; idx < 8 * 128; idx += 384) {
        const int r = idx >> 7, k = idx & 127;
        h0_s[r][k] = hin[(img0 + r) * 128 + k];
    }
    __syncthreads();

    // gi = xin @ w_ih.T + b_ih ; gh = h0 @ w_hh.T + b_hh   (o = t, 8 rows each)
    {
        const int o = t;
        float gi[8], gh[8];
        const float bi = b_ih[o], bh = b_hh[o];
#pragma unroll
        for (int r = 0; r < 8; ++r) { gi[r] = bi; gh[r] = bh; }
        const float* wi = w_ih + o * 168;
        const float* wh = w_hh + o * 128;
        for (int k = 0; k < 128; ++k) {
            const float wv = wi[k];
            const float wvh = wh[k];
#pragma unroll
            for (int r = 0; r < 8; ++r) {
                gi[r] = fmaf(wv, xin_s[r][k], gi[r]);
                gh[r] = fmaf(wvh, h0_s[r][k], gh[r]);
            }
        }
        for (int k = 128; k < 168; ++k) {
            const float wv = wi[k];
#pragma unroll
            for (int r = 0; r < 8; ++r) gi[r] = fmaf(wv, xin_s[r][k], gi[r]);
        }
#pragma unroll
        for (int r = 0; r < 8; ++r) { gis[r][o] = gi[r]; ghs[r][o] = gh[r]; }
    }
    __syncthreads();

    // gates + h_new
    if (t < 128) {
#pragma unroll
        for (int r = 0; r < 8; ++r) {
            const float rg = 1.f / (1.f + expf(-(gis[r][t] + ghs[r][t])));
            const float z  = 1.f / (1.f + expf(-(gis[r][128 + t] + ghs[r][128 + t])));
            const float n  = tanhf(gis[r][256 + t] + rg * ghs[r][256 + t]);
            const float hn = (1.f - z) * n + z * h0_s[r][t];
            hn_s[r][t] = hn;
            out[BATCH * 6 + (img0 + r) * 128 + t] = hn;
        }
    }
    __syncthreads();

    // head: logits = h_new @ head_w.T + head_b
    if (t < 48) {
        const int r = t / 6, j = t - r * 6;
        float acc = head_b[j];
        const float* w = head_w + j * 128;
        for (int k = 0; k < 128; ++k) acc = fmaf(hn_s[r][k], w[k], acc);
        out[(img0 + r) * 6 + j] = acc;
    }
}

extern "C" void kernel_launch(void* const* d_in, const int* in_sizes, int n_in,
                              void* d_out, int out_size, void* d_ws, size_t ws_size,
                              hipStream_t stream) {
    const float* board = (const float*)d_in[0];
    const float* h     = (const float*)d_in[1];
    const int*   atok  = (const int*)d_in[2];
    const int*   uidx  = (const int*)d_in[3];
    const float* w1 = (const float*)d_in[4];
    const float* b1 = (const float*)d_in[5];
    const float* w2 = (const float*)d_in[6];
    const float* b2 = (const float*)d_in[7];
    const float* w3 = (const float*)d_in[8];
    const float* b3 = (const float*)d_in[9];
    const float* w4 = (const float*)d_in[10];
    const float* b4 = (const float*)d_in[11];
    const float* pw = (const float*)d_in[12];
    const float* pb = (const float*)d_in[13];
    const float* emb  = (const float*)d_in[14];
    const float* w_ih = (const float*)d_in[15];
    const float* w_hh = (const float*)d_in[16];
    const float* b_ih = (const float*)d_in[17];
    const float* b_hh = (const float*)d_in[18];
    const float* head_w = (const float*)d_in[19];
    const float* head_b = (const float*)d_in[20];
    float* out = (float*)d_out;

    float* bf = out + BATCH * 6;   // stash CNN features in the h_new output region
    cnn_fused_kernel<<<BATCH, 256, 0, stream>>>(board, w1, b1, w2, b2, w3, b3,
                                                w4, b4, pw, pb, bf);
    gru_kernel<<<BATCH / 8, 384, 0, stream>>>(h, atok, uidx, emb, w_ih, w_hh,
                                              b_ih, b_hh, head_w, head_b, out);
}

// Round 2
// 301.097 us; speedup vs baseline: 27.8218x; 27.8218x over previous
//
#include <hip/hip_runtime.h>
#include <hip/hip_bf16.h>

#define BATCH 4096

typedef __attribute__((ext_vector_type(8))) short short8;
typedef __attribute__((ext_vector_type(16))) float f32x16;

// ---------------- LDS layout (byte offsets) ----------------
// a1: bf16 [34][34][16]  (conv1 out, padded, channel-last)      36992 B
// a2: bf16 [18][18][40]  (pooled conv2, padded, 32ch + 8 pad)   25920 B
// u3: union { sb f32 [34][34] (4624 B) | a3 bf16 [10][10][72] } 14400 B
// meanv: f32[128]                                                 512 B
// w1s:  f32[160] (w1 144 + b1 16)                                 640 B
#define A1_OFF 0
#define A2_OFF 36992
#define U3_OFF 62912
#define MEAN_OFF 77312
#define W1_OFF 77824
#define SMEM_BYTES 78464

// d_ws element offsets (bf16): wb2 @0 (4608), wb3 @4608 (18432), wb4 @23040 (73728)
#define WB3_ELEM 4608
#define WB4_ELEM 23040
#define WB_TOTAL 96768

static __device__ __forceinline__ unsigned pack2(float a, float b) {
    __hip_bfloat16 lo = __float2bfloat16(a), hi = __float2bfloat16(b);
    unsigned short ul = *(unsigned short*)&lo, uh = *(unsigned short*)&hi;
    return ((unsigned)uh << 16) | ul;
}

// ---------------------------------------------------------------------------
// Weight repack: OIHW f32 -> [oc][tap][ic] bf16 (k-contiguous for A-frags)
// ---------------------------------------------------------------------------
__global__ void prepack_weights(const float* __restrict__ w2,
                                const float* __restrict__ w3,
                                const float* __restrict__ w4,
                                __hip_bfloat16* __restrict__ wb) {
    int g = blockIdx.x * 256 + threadIdx.x;
    if (g < 4608) {
        int oc = g / 144, r = g - oc * 144, tap = r >> 4, ic = r & 15;
        wb[g] = __float2bfloat16(w2[oc * 144 + ic * 9 + tap]);
    } else if (g < WB4_ELEM) {
        int gg = g - WB3_ELEM;
        int oc = gg / 288, r = gg - oc * 288, tap = r >> 5, ic = r & 31;
        wb[g] = __float2bfloat16(w3[oc * 288 + ic * 9 + tap]);
    } else if (g < WB_TOTAL) {
        int gg = g - WB4_ELEM;
        int oc = gg / 576, r = gg - oc * 576, tap = r >> 6, ic = r & 63;
        wb[g] = __float2bfloat16(w4[oc * 576 + ic * 9 + tap]);
    }
}

// ---------------------------------------------------------------------------
// Fused CNN, MFMA version. One block (256 thr, 4 waves) per image.
// ---------------------------------------------------------------------------
__global__ __launch_bounds__(256, 2) void cnn_fused_kernel(
    const float* __restrict__ board,
    const float* __restrict__ w1, const float* __restrict__ b1,
    const float* __restrict__ b2, const float* __restrict__ b3,
    const float* __restrict__ b4,
    const float* __restrict__ pw, const float* __restrict__ pb,
    const __hip_bfloat16* __restrict__ wb,
    float* __restrict__ bf_out)
{
    __shared__ alignas(16) char smem[SMEM_BYTES];
    char* a1b = smem + A1_OFF;
    char* a2b = smem + A2_OFF;
    float* sb = (float*)(smem + U3_OFF);
    char* a3b = smem + U3_OFF;
    float* meanv = (float*)(smem + MEAN_OFF);
    float* w1s = (float*)(smem + W1_OFF);

    const int t = threadIdx.x;
    const int img = blockIdx.x;
    const int w = t >> 6;          // wave 0..3
    const int l = t & 63;          // lane
    const int n = l & 31;
    const int h = l >> 5;

    const char* wb2 = (const char*)wb;                    // bytes
    const char* wb3 = (const char*)(wb + WB3_ELEM);
    const char* wb4 = (const char*)(wb + WB4_ELEM);

    // ---- phase A: zero a1+a2+sb, stage w1/b1 ----
    {
        uint4 z; z.x = z.y = z.z = z.w = 0u;
        for (int i = t; i < 67536 / 16; i += 256) ((uint4*)smem)[i] = z;
        if (t < 144) w1s[t] = w1[t];
        else if (t < 160) w1s[t] = b1[t - 144];
    }
    __syncthreads();

    // ---- phase B: load board interior ----
    for (int p = t; p < 1024; p += 256)
        sb[((p >> 5) + 1) * 34 + (p & 31) + 1] = board[img * 1024 + p];
    __syncthreads();

    // ---- conv1 (VALU): 1->16, write a1 channel-last bf16 ----
    {
        const int ocg = t & 3;                 // 4 oc each
        float wv[4][9], bj[4];
#pragma unroll
        for (int j = 0; j < 4; ++j) {
#pragma unroll
            for (int k = 0; k < 9; ++k) wv[j][k] = w1s[(ocg * 4 + j) * 9 + k];
            bj[j] = w1s[144 + ocg * 4 + j];
        }
        for (int it = 0; it < 16; ++it) {
            const int p = (t >> 2) + (it << 6);
            const int y = p >> 5, x = p & 31;
            float v[9];
#pragma unroll
            for (int dy = 0; dy < 3; ++dy)
#pragma unroll
                for (int dx = 0; dx < 3; ++dx)
                    v[dy * 3 + dx] = sb[(y + dy) * 34 + x + dx];
            float av[4];
#pragma unroll
            for (int j = 0; j < 4; ++j) {
                float a = bj[j];
#pragma unroll
                for (int k = 0; k < 9; ++k) a = fmaf(v[k], wv[j][k], a);
                av[j] = fmaxf(a, 0.f);
            }
            uint2 u;
            u.x = pack2(av[0], av[1]);
            u.y = pack2(av[2], av[3]);
            *(uint2*)(a1b + ((y + 1) * 34 + (x + 1)) * 32 + ocg * 8) = u;
        }
    }
    __syncthreads();

    // ---- conv2 (MFMA): 16->32, relu+pool -> a2 [18][18][40] ----
    {
        // zero a3 region (sb is dead) for conv4's padded reads
        uint4 z; z.x = z.y = z.z = z.w = 0u;
        for (int i = t; i < 900; i += 256) ((uint4*)a3b)[i] = z;

        short8 A[9];
#pragma unroll
        for (int tp = 0; tp < 9; ++tp)
            A[tp] = *(const short8*)(wb2 + (n * 144 + tp * 16 + h * 8) * 2);
        float bias[16];
#pragma unroll
        for (int r = 0; r < 16; ++r) bias[r] = b2[(r & 3) + 8 * (r >> 2) + 4 * h];

#pragma unroll 1
        for (int pr = 0; pr < 4; ++pr) {
            const int y0 = 8 * w + 2 * pr;           // output row pair y0, y0+1
            short8 B[4][3];
#pragma unroll
            for (int rr = 0; rr < 4; ++rr)
#pragma unroll
                for (int dx = 0; dx < 3; ++dx)
                    B[rr][dx] = *(const short8*)(a1b + ((y0 + rr) * 34 + n + dx) * 32 + h * 16);
            f32x16 accA = (f32x16)0.0f, accB = (f32x16)0.0f;
#pragma unroll
            for (int dy = 0; dy < 3; ++dy)
#pragma unroll
                for (int dx = 0; dx < 3; ++dx) {
                    accA = __builtin_amdgcn_mfma_f32_32x32x16_bf16(A[dy * 3 + dx], B[dy][dx], accA, 0, 0, 0);
                    accB = __builtin_amdgcn_mfma_f32_32x32x16_bf16(A[dy * 3 + dx], B[dy + 1][dx], accB, 0, 0, 0);
                }
            // epilogue: 2x2 maxpool + bias + relu, pack to a2
            float v[16];
#pragma unroll
            for (int r = 0; r < 16; ++r) {
                float m = fmaxf(accA[r], accB[r]);
                m = fmaxf(m, __shfl_xor(m, 1));
                v[r] = fmaxf(m + bias[r], 0.f);
            }
            const int py = y0 >> 1, px = n >> 1;
            const int qb = (n & 1) * 2;
            char* dst = a2b + ((py + 1) * 18 + (px + 1)) * 80;
#pragma unroll
            for (int qq = 0; qq < 2; ++qq) {
                const int q = qb + qq;
                uint2 u;
                u.x = pack2(v[4 * q + 0], v[4 * q + 1]);
                u.y = pack2(v[4 * q + 2], v[4 * q + 3]);
                *(uint2*)(dst + (8 * q + 4 * h) * 2) = u;
            }
        }
    }
    __syncthreads();

    // ---- conv3 (MFMA): 32->64, relu+pool -> a3 [10][10][72] ----
    {
        const int mt = w >> 1;                  // oc tile (32)
        const int ntb = 4 * (w & 1);            // 4 n-tiles per wave
        short8 A[18];
#pragma unroll
        for (int ks = 0; ks < 18; ++ks) {
            const int tp = ks >> 1, kh = ks & 1;
            A[ks] = *(const short8*)(wb3 + ((mt * 32 + n) * 288 + tp * 32 + kh * 16 + h * 8) * 2);
        }
        float bias[16];
#pragma unroll
        for (int r = 0; r < 16; ++r) bias[r] = b3[32 * mt + (r & 3) + 8 * (r >> 2) + 4 * h];

#pragma unroll 1
        for (int ni = 0; ni < 4; ++ni) {
            const int nt = ntb + ni;
            const int yy = 2 * nt + (n >> 4), x = n & 15;
            const int base = (yy * 18 + x) * 80 + h * 16;
            f32x16 acc = (f32x16)0.0f;
#pragma unroll
            for (int ks = 0; ks < 18; ++ks) {
                const int tp = ks >> 1, kh = ks & 1;
                const int dy = tp / 3, dx = tp - 3 * dy;
                short8 B = *(const short8*)(a2b + base + dy * 1440 + dx * 80 + kh * 32);
                acc = __builtin_amdgcn_mfma_f32_32x32x16_bf16(A[ks], B, acc, 0, 0, 0);
            }
            float v[16];
#pragma unroll
            for (int r = 0; r < 16; ++r) {
                float m = fmaxf(acc[r], __shfl_xor(acc[r], 16));
                m = fmaxf(m, __shfl_xor(m, 1));
                v[r] = fmaxf(m + bias[r], 0.f);
            }
            if (n < 16) {
                const int py = nt, px = (n & 15) >> 1;
                const int qb = (n & 1) * 2;
                char* dst = a3b + ((py + 1) * 10 + (px + 1)) * 144;
#pragma unroll
                for (int qq = 0; qq < 2; ++qq) {
                    const int q = qb + qq;
                    uint2 u;
                    u.x = pack2(v[4 * q + 0], v[4 * q + 1]);
                    u.y = pack2(v[4 * q + 2], v[4 * q + 3]);
                    *(uint2*)(dst + (32 * mt + 8 * q + 4 * h) * 2) = u;
                }
            }
        }
    }
    __syncthreads();

    // ---- conv4 (MFMA): 64->128, relu + global avg -> meanv ----
    {
        const int mt = w;                     // oc = 32w..32w+31
        float bias[16];
#pragma unroll
        for (int r = 0; r < 16; ++r) bias[r] = b4[32 * mt + (r & 3) + 8 * (r >> 2) + 4 * h];
        const int x = n & 7, yq = n >> 3;
        const int base0 = ((yq) * 10 + x) * 144 + h * 16;        // rows 0..3
        const int base1 = ((yq + 4) * 10 + x) * 144 + h * 16;    // rows 4..7
        f32x16 acc0 = (f32x16)0.0f, acc1 = (f32x16)0.0f;
#pragma unroll
        for (int tp = 0; tp < 9; ++tp) {
            const int dy = tp / 3, dx = tp - 3 * dy;
#pragma unroll
            for (int ks = 0; ks < 4; ++ks) {
                short8 A = *(const short8*)(wb4 + ((32 * mt + n) * 576 + tp * 64 + ks * 16 + h * 8) * 2);
                short8 B0 = *(const short8*)(a3b + base0 + dy * 1440 + dx * 144 + ks * 32);
                short8 B1 = *(const short8*)(a3b + base1 + dy * 1440 + dx * 144 + ks * 32);
                acc0 = __builtin_amdgcn_mfma_f32_32x32x16_bf16(A, B0, acc0, 0, 0, 0);
                acc1 = __builtin_amdgcn_mfma_f32_32x32x16_bf16(A, B1, acc1, 0, 0, 0);
            }
        }
        float s[16];
#pragma unroll
        for (int r = 0; r < 16; ++r)
            s[r] = fmaxf(acc0[r] + bias[r], 0.f) + fmaxf(acc1[r] + bias[r], 0.f);
#pragma unroll
        for (int r = 0; r < 16; ++r) {
            float x2 = s[r];
            x2 += __shfl_xor(x2, 1);
            x2 += __shfl_xor(x2, 2);
            x2 += __shfl_xor(x2, 4);
            x2 += __shfl_xor(x2, 8);
            x2 += __shfl_xor(x2, 16);
            s[r] = x2;
        }
        if (n == 0) {
#pragma unroll
            for (int r = 0; r < 16; ++r)
                meanv[32 * mt + (r & 3) + 8 * (r >> 2) + 4 * h] = s[r] * (1.f / 64.f);
        }
    }
    __syncthreads();

    // ---- proj (VALU) ----
    if (t < 128) {
        float acc = pb[t];
        const float* wrow = pw + t * 128;
        for (int k = 0; k < 128; ++k) acc = fmaf(meanv[k], wrow[k], acc);
        bf_out[img * 128 + t] = acc;
    }
}

// ---------------------------------------------------------------------------
// Kernel B: GRU step + head (unchanged from round 1).
// ---------------------------------------------------------------------------
__global__ __launch_bounds__(384) void gru_kernel(
    const float* __restrict__ hin,
    const int* __restrict__ atok, const int* __restrict__ uidx,
    const float* __restrict__ emb,
    const float* __restrict__ w_ih, const float* __restrict__ w_hh,
    const float* __restrict__ b_ih, const float* __restrict__ b_hh,
    const float* __restrict__ head_w, const float* __restrict__ head_b,
    float* __restrict__ out)
{
    const int img0 = blockIdx.x * 8;
    const int t = threadIdx.x;
    __shared__ float xin_s[8][168];
    __shared__ float h0_s[8][128];
    __shared__ float gis[8][384];
    __shared__ float ghs[8][384];
    __shared__ float hn_s[8][128];
    const float* bf = out + BATCH * 6;

    for (int idx = t; idx < 8 * 168; idx += 384) {
        const int r = idx / 168, k = idx - r * 168;
        const int row = img0 + r;
        float v;
        if (k < 128)      v = bf[row * 128 + k];
        else if (k < 136) v = (float)((atok[row] >> (k - 128)) & 1);
        else              v = emb[uidx[row] * 32 + (k - 136)];
        xin_s[r][k] = v;
    }
    for (int idx = t; idx < 8 * 128; idx += 384) {
        const int r = idx >> 7, k = idx & 127;
        h0_s[r][k] = hin[(img0 + r) * 128 + k];
    }
    __syncthreads();

    {
        const int o = t;
        float gi[8], gh[8];
        const float bi = b_ih[o], bh = b_hh[o];
#pragma unroll
        for (int r = 0; r < 8; ++r) { gi[r] = bi; gh[r] = bh; }
        const float* wi = w_ih + o * 168;
        const float* wh = w_hh + o * 128;
        for (int k = 0; k < 128; ++k) {
            const float wv = wi[k];
            const float wvh = wh[k];
#pragma unroll
            for (int r = 0; r < 8; ++r) {
                gi[r] = fmaf(wv, xin_s[r][k], gi[r]);
                gh[r] = fmaf(wvh, h0_s[r][k], gh[r]);
            }
        }
        for (int k = 128; k < 168; ++k) {
            const float wv = wi[k];
#pragma unroll
            for (int r = 0; r < 8; ++r) gi[r] = fmaf(wv, xin_s[r][k], gi[r]);
        }
#pragma unroll
        for (int r = 0; r < 8; ++r) { gis[r][o] = gi[r]; ghs[r][o] = gh[r]; }
    }
    __syncthreads();

    if (t < 128) {
#pragma unroll
        for (int r = 0; r < 8; ++r) {
            const float rg = 1.f / (1.f + expf(-(gis[r][t] + ghs[r][t])));
            const float z  = 1.f / (1.f + expf(-(gis[r][128 + t] + ghs[r][128 + t])));
            const float nn = tanhf(gis[r][256 + t] + rg * ghs[r][256 + t]);
            const float hn = (1.f - z) * nn + z * h0_s[r][t];
            hn_s[r][t] = hn;
            out[BATCH * 6 + (img0 + r) * 128 + t] = hn;
        }
    }
    __syncthreads();

    if (t < 48) {
        const int r = t / 6, j = t - r * 6;
        float acc = head_b[j];
        const float* wrow = head_w + j * 128;
        float a2 = acc;
        for (int k = 0; k < 128; ++k) a2 = fmaf(hn_s[r][k], wrow[k], a2);
        out[(img0 + r) * 6 + j] = a2;
    }
}

extern "C" void kernel_launch(void* const* d_in, const int* in_sizes, int n_in,
                              void* d_out, int out_size, void* d_ws, size_t ws_size,
                              hipStream_t stream) {
    const float* board = (const float*)d_in[0];
    const float* h     = (const float*)d_in[1];
    const int*   atok  = (const int*)d_in[2];
    const int*   uidx  = (const int*)d_in[3];
    const float* w1 = (const float*)d_in[4];
    const float* b1 = (const float*)d_in[5];
    const float* w2 = (const float*)d_in[6];
    const float* b2 = (const float*)d_in[7];
    const float* w3 = (const float*)d_in[8];
    const float* b3 = (const float*)d_in[9];
    const float* w4 = (const float*)d_in[10];
    const float* b4 = (const float*)d_in[11];
    const float* pw = (const float*)d_in[12];
    const float* pb = (const float*)d_in[13];
    const float* emb  = (const float*)d_in[14];
    const float* w_ih = (const float*)d_in[15];
    const float* w_hh = (const float*)d_in[16];
    const float* b_ih = (const float*)d_in[17];
    const float* b_hh = (const float*)d_in[18];
    const float* head_w = (const float*)d_in[19];
    const float* head_b = (const float*)d_in[20];
    float* out = (float*)d_out;
    __hip_bfloat16* wb = (__hip_bfloat16*)d_ws;

    float* bf = out + BATCH * 6;
    prepack_weights<<<(WB_TOTAL + 255) / 256, 256, 0, stream>>>(w2, w3, w4, wb);
    cnn_fused_kernel<<<BATCH, 256, 0, stream>>>(board, w1, b1, b2, b3, b4,
                                                pw, pb, wb, bf);
    gru_kernel<<<BATCH / 8, 384, 0, stream>>>(h, atok, uidx, emb, w_ih, w_hh,
                                              b_ih, b_hh, head_w, head_b, out);
}

// Round 3
// 300.123 us; speedup vs baseline: 27.9121x; 1.0032x over previous
//
#include <hip/hip_runtime.h>
#include <hip/hip_bf16.h>

#define BATCH 4096

typedef __attribute__((ext_vector_type(8))) short short8;
typedef __attribute__((ext_vector_type(16))) float f32x16;

// ---------------- d_ws layout ----------------
// a2g: bf16 [4096][16][16][32]  (pooled conv2, channel-last)  67,108,864 B
// wb:  bf16 weights after that: wb1 @0 (512), wb2 @512 (4608),
//      wb3 @5120 (18432), wb4 @23552 (73728)  -> 97280 elems
#define A2G_BYTES 67108864
#define WB1_ELEM 0
#define WB2_ELEM 512
#define WB3_ELEM 5120
#define WB4_ELEM 23552
#define WB_TOTAL 97280

static __device__ __forceinline__ unsigned pack2(float a, float b) {
    __hip_bfloat16 lo = __float2bfloat16(a), hi = __float2bfloat16(b);
    unsigned short ul = *(unsigned short*)&lo, uh = *(unsigned short*)&hi;
    return ((unsigned)uh << 16) | ul;
}

// ---------------------------------------------------------------------------
// Weight repack.
// wb1: [oc 32][k 16]  (oc>=16 or k>=9 -> 0), k = tap
// wb2/3/4: [oc][tap 9][ic] bf16, k-contiguous per tap
// ---------------------------------------------------------------------------
__global__ void prepack_weights(const float* __restrict__ w1,
                                const float* __restrict__ w2,
                                const float* __restrict__ w3,
                                const float* __restrict__ w4,
                                __hip_bfloat16* __restrict__ wb) {
    int g = blockIdx.x * 256 + threadIdx.x;
    if (g < 512) {
        int oc = g >> 4, k = g & 15;
        float v = (oc < 16 && k < 9) ? w1[oc * 9 + k] : 0.f;
        wb[g] = __float2bfloat16(v);
    } else if (g < WB3_ELEM) {
        int gg = g - WB2_ELEM;
        int oc = gg / 144, r = gg - oc * 144, tap = r >> 4, ic = r & 15;
        wb[g] = __float2bfloat16(w2[oc * 144 + ic * 9 + tap]);
    } else if (g < WB4_ELEM) {
        int gg = g - WB3_ELEM;
        int oc = gg / 288, r = gg - oc * 288, tap = r >> 5, ic = r & 31;
        wb[g] = __float2bfloat16(w3[oc * 288 + ic * 9 + tap]);
    } else if (g < WB_TOTAL) {
        int gg = g - WB4_ELEM;
        int oc = gg / 576, r = gg - oc * 576, tap = r >> 6, ic = r & 63;
        wb[g] = __float2bfloat16(w4[oc * 576 + ic * 9 + tap]);
    }
}

// ---------------------------------------------------------------------------
// Kernel A: conv1 (MFMA, taps as K) + conv2 (MFMA) + pool -> a2g (global).
// LDS: sbb bf16 [34][34] @0 (2312, pad 2320) + a1 bf16 [34][34][16] @2320
// total 39312 B -> 4 blocks/CU.
// ---------------------------------------------------------------------------
__global__ __launch_bounds__(256, 4) void cnn12_kernel(
    const float* __restrict__ board,
    const float* __restrict__ b1, const float* __restrict__ b2,
    const __hip_bfloat16* __restrict__ wb,
    __hip_bfloat16* __restrict__ a2g)
{
    __shared__ alignas(16) char smem[39312];
    unsigned short* sbu = (unsigned short*)smem;     // bf16 board [34][34]
    char* a1b = smem + 2320;                         // bf16 [34][34][16]

    const int t = threadIdx.x;
    const int img = blockIdx.x;
    const int w = t >> 6;
    const int l = t & 63;
    const int n = l & 31;
    const int h = l >> 5;

    // ---- zero sbb + a1 ----
    {
        uint4 z; z.x = z.y = z.z = z.w = 0u;
        for (int i = t; i < 39312 / 16; i += 256) ((uint4*)smem)[i] = z;
    }
    __syncthreads();

    // ---- load board (f32 -> bf16, padded interior) ----
    {
        float4 v = ((const float4*)board)[img * 256 + t];
        const int p0 = t * 4;
        const int row = (p0 >> 5) + 1, col = (p0 & 31) + 1;
        unsigned short* d = sbu + row * 34 + col;
        __hip_bfloat16 b0 = __float2bfloat16(v.x), b1v = __float2bfloat16(v.y);
        __hip_bfloat16 b2v = __float2bfloat16(v.z), b3v = __float2bfloat16(v.w);
        d[0] = *(unsigned short*)&b0; d[1] = *(unsigned short*)&b1v;
        d[2] = *(unsigned short*)&b2v; d[3] = *(unsigned short*)&b3v;
    }
    __syncthreads();

    // ---- conv1 (MFMA): A = w1 [32oc x 16k], B = board taps; relu -> a1 ----
    {
        short8 A1 = *(const short8*)((const char*)wb + (n * 16 + h * 8) * 2);
        float b1s[8];
#pragma unroll
        for (int r = 0; r < 8; ++r) b1s[r] = b1[(r & 3) + 8 * (r >> 2) + 4 * h];
#pragma unroll 1
        for (int y8 = 0; y8 < 8; ++y8) {
            const int y = 8 * w + y8;            // output row 0..31
            short8 Bv;
            if (h == 0) {
#pragma unroll
                for (int j = 0; j < 8; ++j)
                    Bv[j] = (short)sbu[(y + j / 3) * 34 + n + (j % 3)];
            } else {
                Bv[0] = (short)sbu[(y + 2) * 34 + n + 2];
#pragma unroll
                for (int j = 1; j < 8; ++j) Bv[j] = 0;
            }
            f32x16 acc = __builtin_amdgcn_mfma_f32_32x32x16_bf16(A1, Bv, (f32x16)0.0f, 0, 0, 0);
            float v[8];
#pragma unroll
            for (int r = 0; r < 8; ++r) v[r] = fmaxf(acc[r] + b1s[r], 0.f);
            uint2 u0, u1;
            u0.x = pack2(v[0], v[1]); u0.y = pack2(v[2], v[3]);
            u1.x = pack2(v[4], v[5]); u1.y = pack2(v[6], v[7]);
            char* dst = a1b + ((y + 1) * 34 + (n + 1)) * 32 + h * 8;
            *(uint2*)dst = u0;
            *(uint2*)(dst + 16) = u1;
        }
    }
    __syncthreads();

    // ---- conv2 (MFMA): 16->32, relu + 2x2 maxpool -> a2g ----
    {
        const char* wb2 = (const char*)(wb + WB2_ELEM);
        short8 A[9];
#pragma unroll
        for (int tp = 0; tp < 9; ++tp)
            A[tp] = *(const short8*)(wb2 + (n * 144 + tp * 16 + h * 8) * 2);
        float bias[16];
#pragma unroll
        for (int r = 0; r < 16; ++r) bias[r] = b2[(r & 3) + 8 * (r >> 2) + 4 * h];

#pragma unroll 1
        for (int pr = 0; pr < 4; ++pr) {
            const int y0 = 8 * w + 2 * pr;       // output row pair y0, y0+1
            short8 B[4][3];
#pragma unroll
            for (int rr = 0; rr < 4; ++rr)
#pragma unroll
                for (int dx = 0; dx < 3; ++dx)
                    B[rr][dx] = *(const short8*)(a1b + ((y0 + rr) * 34 + n + dx) * 32 + h * 16);
            f32x16 accA = (f32x16)0.0f, accB = (f32x16)0.0f;
#pragma unroll
            for (int dy = 0; dy < 3; ++dy)
#pragma unroll
                for (int dx = 0; dx < 3; ++dx) {
                    accA = __builtin_amdgcn_mfma_f32_32x32x16_bf16(A[dy * 3 + dx], B[dy][dx], accA, 0, 0, 0);
                    accB = __builtin_amdgcn_mfma_f32_32x32x16_bf16(A[dy * 3 + dx], B[dy + 1][dx], accB, 0, 0, 0);
                }
            float v[16];
#pragma unroll
            for (int r = 0; r < 16; ++r) {
                float m = fmaxf(accA[r], accB[r]);
                m = fmaxf(m, __shfl_xor(m, 1));
                v[r] = fmaxf(m + bias[r], 0.f);
            }
            const int py = y0 >> 1, px = n >> 1;
            const int qb = (n & 1) * 2;
            __hip_bfloat16* gdst = a2g + (size_t)img * 8192 + (py * 16 + px) * 32;
#pragma unroll
            for (int qq = 0; qq < 2; ++qq) {
                const int q = qb + qq;
                uint2 u;
                u.x = pack2(v[4 * q + 0], v[4 * q + 1]);
                u.y = pack2(v[4 * q + 2], v[4 * q + 3]);
                *(uint2*)(gdst + 8 * q + 4 * h) = u;
            }
        }
    }
}

// ---------------------------------------------------------------------------
// Kernel B: conv3 (MFMA) + conv4 (MFMA, swizzled a3) + avgpool + proj.
// LDS: a2 [18][18][40] @0 (25920) + a3 [10][10][72] @25920 (14400, XOR-swz)
//      + meanv f32[128] @40320 -> 40832 B -> 4 blocks/CU.
// ---------------------------------------------------------------------------
__global__ __launch_bounds__(256, 4) void cnn34_kernel(
    const __hip_bfloat16* __restrict__ a2g,
    const float* __restrict__ b3, const float* __restrict__ b4,
    const float* __restrict__ pw, const float* __restrict__ pb,
    const __hip_bfloat16* __restrict__ wb,
    float* __restrict__ bf_out)
{
    __shared__ alignas(16) char smem[40832];
    char* a2b = smem;
    char* a3b = smem + 25920;
    float* meanv = (float*)(smem + 40320);

    const int t = threadIdx.x;
    const int img = blockIdx.x;
    const int w = t >> 6;
    const int l = t & 63;
    const int n = l & 31;
    const int h = l >> 5;

    const char* wb3 = (const char*)(wb + WB3_ELEM);
    const char* wb4 = (const char*)(wb + WB4_ELEM);

    // ---- zero a2+a3 (borders + pad) ----
    {
        uint4 z; z.x = z.y = z.z = z.w = 0u;
        for (int i = t; i < 40320 / 16; i += 256) ((uint4*)smem)[i] = z;
    }
    __syncthreads();

    // ---- load a2 interior from global ----
    for (int i = t; i < 1024; i += 256) {
        const int p = i >> 2, c4 = i & 3;        // pixel, 16B-chunk
        const int py = p >> 4, px = p & 15;
        uint4 v = *(const uint4*)(a2g + (size_t)img * 8192 + p * 32 + c4 * 8);
        *(uint4*)(a2b + ((py + 1) * 18 + (px + 1)) * 80 + c4 * 16) = v;
    }
    __syncthreads();

    // ---- conv3 (MFMA): 32->64, relu+pool -> a3 (XOR-swizzled channels) ----
    {
        const int mt = w >> 1;                   // oc tile
        const int ntb = 4 * (w & 1);
        short8 A[18];
#pragma unroll
        for (int ks = 0; ks < 18; ++ks) {
            const int tp = ks >> 1, kh = ks & 1;
            A[ks] = *(const short8*)(wb3 + ((mt * 32 + n) * 288 + tp * 32 + kh * 16 + h * 8) * 2);
        }
        float bias[16];
#pragma unroll
        for (int r = 0; r < 16; ++r) bias[r] = b3[32 * mt + (r & 3) + 8 * (r >> 2) + 4 * h];

#pragma unroll 1
        for (int ni = 0; ni < 4; ++ni) {
            const int nt = ntb + ni;
            const int yy = 2 * nt + (n >> 4), x = n & 15;
            const int base = (yy * 18 + x) * 80 + h * 16;
            f32x16 acc = (f32x16)0.0f;
#pragma unroll
            for (int ks = 0; ks < 18; ++ks) {
                const int tp = ks >> 1, kh = ks & 1;
                const int dy = tp / 3, dx = tp - 3 * dy;
                short8 B = *(const short8*)(a2b + base + dy * 1440 + dx * 80 + kh * 32);
                acc = __builtin_amdgcn_mfma_f32_32x32x16_bf16(A[ks], B, acc, 0, 0, 0);
            }
            float v[16];
#pragma unroll
            for (int r = 0; r < 16; ++r) {
                float m = fmaxf(acc[r], __shfl_xor(acc[r], 16));
                m = fmaxf(m, __shfl_xor(m, 1));
                v[r] = fmaxf(m + bias[r], 0.f);
            }
            if (n < 16) {
                const int py = nt, px = (n & 15) >> 1;
                const int pc = px + 1;
                const int key = (pc & 3) << 5;
                char* pixb = a3b + ((py + 1) * 10 + pc) * 144;
                const int qb = (n & 1) * 2;
#pragma unroll
                for (int qq = 0; qq < 2; ++qq) {
                    const int q = qb + qq;
                    uint2 u;
                    u.x = pack2(v[4 * q + 0], v[4 * q + 1]);
                    u.y = pack2(v[4 * q + 2], v[4 * q + 3]);
                    *(uint2*)(pixb + ((64 * mt + 16 * q + 8 * h) ^ key)) = u;
                }
            }
        }
    }
    __syncthreads();

    // ---- conv4 (MFMA): 64->128, relu + global avg -> meanv ----
    {
        const int mt = w;
        float bias[16];
#pragma unroll
        for (int r = 0; r < 16; ++r) bias[r] = b4[32 * mt + (r & 3) + 8 * (r >> 2) + 4 * h];
        const int x = n & 7, yq = n >> 3;
        f32x16 acc0 = (f32x16)0.0f, acc1 = (f32x16)0.0f;
#pragma unroll
        for (int dy = 0; dy < 3; ++dy)
#pragma unroll
            for (int dx = 0; dx < 3; ++dx) {
                const int pc = x + dx;                     // padded col 0..9
                const int key = (pc & 3) << 5;
                const char* p0 = a3b + ((yq + dy) * 10 + pc) * 144 + h * 16;
                const char* p1 = a3b + ((yq + 4 + dy) * 10 + pc) * 144 + h * 16;
#pragma unroll
                for (int ks = 0; ks < 4; ++ks) {
                    const int off = (ks * 32) ^ key;
                    short8 A = *(const short8*)(wb4 + ((32 * mt + n) * 576 + (dy * 3 + dx) * 64 + ks * 16 + h * 8) * 2);
                    short8 B0 = *(const short8*)(p0 + off);
                    short8 B1 = *(const short8*)(p1 + off);
                    acc0 = __builtin_amdgcn_mfma_f32_32x32x16_bf16(A, B0, acc0, 0, 0, 0);
                    acc1 = __builtin_amdgcn_mfma_f32_32x32x16_bf16(A, B1, acc1, 0, 0, 0);
                }
            }
        float s[16];
#pragma unroll
        for (int r = 0; r < 16; ++r)
            s[r] = fmaxf(acc0[r] + bias[r], 0.f) + fmaxf(acc1[r] + bias[r], 0.f);
#pragma unroll
        for (int r = 0; r < 16; ++r) {
            float x2 = s[r];
            x2 += __shfl_xor(x2, 1);
            x2 += __shfl_xor(x2, 2);
            x2 += __shfl_xor(x2, 4);
            x2 += __shfl_xor(x2, 8);
            x2 += __shfl_xor(x2, 16);
            s[r] = x2;
        }
        if (n == 0) {
#pragma unroll
            for (int r = 0; r < 16; ++r)
                meanv[32 * mt + (r & 3) + 8 * (r >> 2) + 4 * h] = s[r] * (1.f / 64.f);
        }
    }
    __syncthreads();

    // ---- proj (VALU) ----
    if (t < 128) {
        float acc = pb[t];
        const float* wrow = pw + t * 128;
        for (int k = 0; k < 128; ++k) acc = fmaf(meanv[k], wrow[k], acc);
        bf_out[img * 128 + t] = acc;
    }
}

// ---------------------------------------------------------------------------
// Kernel C: GRU step + head (unchanged).
// ---------------------------------------------------------------------------
__global__ __launch_bounds__(384) void gru_kernel(
    const float* __restrict__ hin,
    const int* __restrict__ atok, const int* __restrict__ uidx,
    const float* __restrict__ emb,
    const float* __restrict__ w_ih, const float* __restrict__ w_hh,
    const float* __restrict__ b_ih, const float* __restrict__ b_hh,
    const float* __restrict__ head_w, const float* __restrict__ head_b,
    float* __restrict__ out)
{
    const int img0 = blockIdx.x * 8;
    const int t = threadIdx.x;
    __shared__ float xin_s[8][168];
    __shared__ float h0_s[8][128];
    __shared__ float gis[8][384];
    __shared__ float ghs[8][384];
    __shared__ float hn_s[8][128];
    const float* bf = out + BATCH * 6;

    for (int idx = t; idx < 8 * 168; idx += 384) {
        const int r = idx / 168, k = idx - r * 168;
        const int row = img0 + r;
        float v;
        if (k < 128)      v = bf[row * 128 + k];
        else if (k < 136) v = (float)((atok[row] >> (k - 128)) & 1);
        else              v = emb[uidx[row] * 32 + (k - 136)];
        xin_s[r][k] = v;
    }
    for (int idx = t; idx < 8 * 128; idx += 384) {
        const int r = idx >> 7, k = idx & 127;
        h0_s[r][k] = hin[(img0 + r) * 128 + k];
    }
    __syncthreads();

    {
        const int o = t;
        float gi[8], gh[8];
        const float bi = b_ih[o], bh = b_hh[o];
#pragma unroll
        for (int r = 0; r < 8; ++r) { gi[r] = bi; gh[r] = bh; }
        const float* wi = w_ih + o * 168;
        const float* wh = w_hh + o * 128;
        for (int k = 0; k < 128; ++k) {
            const float wv = wi[k];
            const float wvh = wh[k];
#pragma unroll
            for (int r = 0; r < 8; ++r) {
                gi[r] = fmaf(wv, xin_s[r][k], gi[r]);
                gh[r] = fmaf(wvh, h0_s[r][k], gh[r]);
            }
        }
        for (int k = 128; k < 168; ++k) {
            const float wv = wi[k];
#pragma unroll
            for (int r = 0; r < 8; ++r) gi[r] = fmaf(wv, xin_s[r][k], gi[r]);
        }
#pragma unroll
        for (int r = 0; r < 8; ++r) { gis[r][o] = gi[r]; ghs[r][o] = gh[r]; }
    }
    __syncthreads();

    if (t < 128) {
#pragma unroll
        for (int r = 0; r < 8; ++r) {
            const float rg = 1.f / (1.f + expf(-(gis[r][t] + ghs[r][t])));
            const float z  = 1.f / (1.f + expf(-(gis[r][128 + t] + ghs[r][128 + t])));
            const float nn = tanhf(gis[r][256 + t] + rg * ghs[r][256 + t]);
            const float hn = (1.f - z) * nn + z * h0_s[r][t];
            hn_s[r][t] = hn;
            out[BATCH * 6 + (img0 + r) * 128 + t] = hn;
        }
    }
    __syncthreads();

    if (t < 48) {
        const int r = t / 6, j = t - r * 6;
        float acc = head_b[j];
        const float* wrow = head_w + j * 128;
        for (int k = 0; k < 128; ++k) acc = fmaf(hn_s[r][k], wrow[k], acc);
        out[(img0 + r) * 6 + j] = acc;
    }
}

extern "C" void kernel_launch(void* const* d_in, const int* in_sizes, int n_in,
                              void* d_out, int out_size, void* d_ws, size_t ws_size,
                              hipStream_t stream) {
    const float* board = (const float*)d_in[0];
    const float* h     = (const float*)d_in[1];
    const int*   atok  = (const int*)d_in[2];
    const int*   uidx  = (const int*)d_in[3];
    const float* w1 = (const float*)d_in[4];
    const float* b1 = (const float*)d_in[5];
    const float* w2 = (const float*)d_in[6];
    const float* b2 = (const float*)d_in[7];
    const float* w3 = (const float*)d_in[8];
    const float* b3 = (const float*)d_in[9];
    const float* w4 = (const float*)d_in[10];
    const float* b4 = (const float*)d_in[11];
    const float* pw = (const float*)d_in[12];
    const float* pb = (const float*)d_in[13];
    const float* emb  = (const float*)d_in[14];
    const float* w_ih = (const float*)d_in[15];
    const float* w_hh = (const float*)d_in[16];
    const float* b_ih = (const float*)d_in[17];
    const float* b_hh = (const float*)d_in[18];
    const float* head_w = (const float*)d_in[19];
    const float* head_b = (const float*)d_in[20];
    float* out = (float*)d_out;

    __hip_bfloat16* a2g = (__hip_bfloat16*)d_ws;
    __hip_bfloat16* wb = (__hip_bfloat16*)((char*)d_ws + A2G_BYTES);
    float* bf = out + BATCH * 6;

    prepack_weights<<<(WB_TOTAL + 255) / 256, 256, 0, stream>>>(w1, w2, w3, w4, wb);
    cnn12_kernel<<<BATCH, 256, 0, stream>>>(board, b1, b2, wb, a2g);
    cnn34_kernel<<<BATCH, 256, 0, stream>>>(a2g, b3, b4, pw, pb, wb, bf);
    gru_kernel<<<BATCH / 8, 384, 0, stream>>>(h, atok, uidx, emb, w_ih, w_hh,
                                              b_ih, b_hh, head_w, head_b, out);
}